// Round 1
// baseline (1084.707 us; speedup 1.0000x reference)
//
#include <hip/hip_runtime.h>

// Problem constants
#define D 4096
#define OBJ 20
#define M_MEM 1000
#define F_ 20
// frames out = Q*B*F = 320; frame elems = OBJ*D = 81920 (=20480 float4)
// out layout: Rp [320*81920] | Rn [320*81920] | high_sim [16] | low_sim [16]
#define FRAME_F4 20480
#define RP_F4 6553600
#define OUT_TAIL 52428800

typedef float vf4 __attribute__((ext_vector_type(4)));

__device__ __forceinline__ float4 f4max(float4 a, float4 b){
  return make_float4(fmaxf(a.x,b.x), fmaxf(a.y,b.y), fmaxf(a.z,b.z), fmaxf(a.w,b.w));
}
__device__ __forceinline__ float4 f4scale(float4 a, float s){
  return make_float4(a.x*s, a.y*s, a.z*s, a.w*s);
}
__device__ __forceinline__ double f4ss(float4 a){
  return (double)a.x*a.x + (double)a.y*a.y + (double)a.z*a.z + (double)a.w*a.w;
}
// nontemporal float4 store (output is never re-read on device)
__device__ __forceinline__ void ntst(float4* p, float4 v){
  vf4 t; t.x = v.x; t.y = v.y; t.z = v.z; t.w = v.w;
  __builtin_nontemporal_store(t, (vf4*)p);
}
// nontemporal float4 load (655 MB mem stream: zero reuse, don't evict L2/L3)
__device__ __forceinline__ float4 ntld(const float4* p){
  vf4 t = __builtin_nontemporal_load((const vf4*)p);
  return make_float4(t.x, t.y, t.z, t.w);
}

// monotone u32 key for float (handles negatives)
__device__ __forceinline__ unsigned int fkey(float f){
  unsigned int b = __float_as_uint(f);
  return (b & 0x80000000u) ? ~b : (b | 0x80000000u);
}

// 256-thread block sum reduce (f64), result broadcast to all threads
__device__ __forceinline__ double blockReduce256(double v){
  #pragma unroll
  for (int off = 32; off > 0; off >>= 1) v += __shfl_down(v, off, 64);
  __shared__ double sh[4];
  int w = threadIdx.x >> 6;
  if ((threadIdx.x & 63) == 0) sh[w] = v;
  __syncthreads();
  return sh[0] + sh[1] + sh[2] + sh[3];
}

// K1: one grid, three roles.
//  blocks 80..2079 : mem max-pool + L2-normalize (the 655 MB stream, NT loads)
//  blocks  0..79   : fused per-frame row norms (wave-per-row) + max-pool + normalize
//  block  2080     : high/low frame selection + zero packed[]
__global__ void k_fused1(const float* __restrict__ x,
                         const float* __restrict__ mem1, const float* __restrict__ mem2,
                         const float* __restrict__ qr, const int* __restrict__ rand_idx,
                         float* __restrict__ mpn1, float* __restrict__ mpn2,
                         float* __restrict__ rmaxn, float* __restrict__ inv_norm,
                         unsigned long long* __restrict__ packed,
                         int* __restrict__ high_idx, int* __restrict__ low_idx){
  int blk = blockIdx.x;
  int tid = threadIdx.x;
  if (blk >= 80 && blk < 2080){
    int id = blk - 80;
    const float* mem; float* outp; int m;
    if (id < M_MEM){ mem = mem1; outp = mpn1; m = id; }
    else           { mem = mem2; outp = mpn2; m = id - M_MEM; }
    const float4* base = (const float4*)mem + (size_t)m * FRAME_F4;
    float4 mv[4];
    #pragma unroll
    for (int i = 0; i < 4; i++) mv[i] = make_float4(-INFINITY,-INFINITY,-INFINITY,-INFINITY);
    for (int o = 0; o < OBJ; o++){
      const float4* p = base + o*1024;
      #pragma unroll
      for (int i = 0; i < 4; i++) mv[i] = f4max(mv[i], ntld(p + tid + i*256));
    }
    double ss = 0.0;
    #pragma unroll
    for (int i = 0; i < 4; i++) ss += f4ss(mv[i]);
    ss = blockReduce256(ss);
    float rinv = (float)(1.0 / fmax(sqrt(ss), 1e-12));
    float4* o4 = (float4*)outp + (size_t)m * 1024;
    #pragma unroll
    for (int i = 0; i < 4; i++) o4[tid + i*256] = f4scale(mv[i], rinv);
  } else if (blk < 80){
    // frame blk = b*20+f. Pass 1: wave w computes norms of rows 5w..5w+4 (no block sync).
    __shared__ float sinv[OBJ];
    int w = tid >> 6, lane = tid & 63;
    const float4* base = (const float4*)x + (size_t)blk * FRAME_F4;
    for (int o = w*5; o < w*5 + 5; o++){
      const float4* p = base + o*1024;
      double ss = 0.0;
      #pragma unroll
      for (int j = 0; j < 16; j++) ss += f4ss(__ldg(p + j*64 + lane));
      #pragma unroll
      for (int off = 32; off > 0; off >>= 1) ss += __shfl_down(ss, off, 64);
      if (lane == 0){
        float inv = (float)(1.0 / fmax(sqrt(ss), 1e-12));
        sinv[o] = inv;
        inv_norm[blk*OBJ + o] = inv;
      }
    }
    __syncthreads();
    // Pass 2: scaled max-pool over rows (re-reads frame from L2) + normalize.
    float4 mv[4];
    #pragma unroll
    for (int i = 0; i < 4; i++) mv[i] = make_float4(-INFINITY,-INFINITY,-INFINITY,-INFINITY);
    for (int o = 0; o < OBJ; o++){
      float s = sinv[o];
      const float4* p = base + o*1024;
      #pragma unroll
      for (int i = 0; i < 4; i++) mv[i] = f4max(mv[i], f4scale(__ldg(p + tid + i*256), s));
    }
    double ss = 0.0;
    #pragma unroll
    for (int i = 0; i < 4; i++) ss += f4ss(mv[i]);
    ss = blockReduce256(ss);
    float rinv = (float)(1.0 / fmax(sqrt(ss), 1e-12));
    float4* outp = (float4*)rmaxn + (size_t)blk * 1024;
    #pragma unroll
    for (int i = 0; i < 4; i++) outp[tid + i*256] = f4scale(mv[i], rinv);
  } else {
    int t = tid;
    if (t < 160) packed[t] = 0ull;
    if (t < 16){
      float wv[F_];
      for (int f = 0; f < F_; f++) wv[f] = qr[t*F_ + f];
      int hi = 0; float hv = wv[0];
      for (int f = 1; f < F_; f++) if (wv[f] > hv){ hv = wv[f]; hi = f; }
      int r = rand_idx[t];
      bool used[F_];
      for (int f = 0; f < F_; f++) used[f] = false;
      used[hi] = true;
      int li = 0;
      for (int it = 0; it <= r; it++){
        int bi = -1; float bv = INFINITY;
        for (int f = 0; f < F_; f++) if (!used[f] && wv[f] < bv){ bv = wv[f]; bi = f; }
        used[bi] = true; li = bi;
      }
      high_idx[t] = hi; low_idx[t] = li;
    }
  }
}

// K2: dots of 80 rmaxn rows vs 4 LDS-staged mem_mpn rows.
// Waves partition bf: each global r-load feeds 4 m-row FMAs (4x less L1 traffic
// than the previous wave-per-m-row layout, which re-loaded r per wave).
// No syncs in the main loop; per-bf shfl reduce + one atomicMax.
__global__ void k_dots(const float* __restrict__ mpn1, const float* __restrict__ mpn2,
                       const float* __restrict__ rmaxn,
                       unsigned long long* __restrict__ packed){
  int blk = blockIdx.x;         // 0..499
  int which = blk / 250;        // 0 -> mem1, 1 -> mem2
  int chunk = blk % 250;        // 4 m-rows per chunk
  const float* mpn = which ? mpn2 : mpn1;
  __shared__ float4 rows[4*1024];   // 64 KB
  const float4* src = (const float4*)mpn + (size_t)chunk * 4096;
  for (int i = threadIdx.x; i < 4096; i += 256) rows[i] = __ldg(src + i);
  __syncthreads();
  int w = threadIdx.x >> 6, lane = threadIdx.x & 63;
  unsigned long long* slot = packed + which*80;
  for (int bf = w; bf < 80; bf += 4){
    const float4* rrow = (const float4*)rmaxn + (size_t)bf * 1024;
    float d0 = 0.f, d1 = 0.f, d2 = 0.f, d3 = 0.f;
    #pragma unroll
    for (int i = 0; i < 16; i++){
      float4 r  = __ldg(rrow + i*64 + lane);
      float4 m0 = rows[       i*64 + lane];
      float4 m1 = rows[1024 + i*64 + lane];
      float4 m2 = rows[2048 + i*64 + lane];
      float4 m3 = rows[3072 + i*64 + lane];
      d0 += r.x*m0.x + r.y*m0.y + r.z*m0.z + r.w*m0.w;
      d1 += r.x*m1.x + r.y*m1.y + r.z*m1.z + r.w*m1.w;
      d2 += r.x*m2.x + r.y*m2.y + r.z*m2.z + r.w*m2.w;
      d3 += r.x*m3.x + r.y*m3.y + r.z*m3.z + r.w*m3.w;
    }
    #pragma unroll
    for (int off = 32; off > 0; off >>= 1){
      d0 += __shfl_down(d0, off, 64);
      d1 += __shfl_down(d1, off, 64);
      d2 += __shfl_down(d2, off, 64);
      d3 += __shfl_down(d3, off, 64);
    }
    if (lane == 0){
      float best = d0; int bi = 0;
      if (d1 > best){ best = d1; bi = 1; }
      if (d2 > best){ best = d2; bi = 2; }
      if (d3 > best){ best = d3; bi = 3; }
      unsigned long long pk = ((unsigned long long)fkey(best) << 32) |
                              (unsigned int)(chunk*4 + bi);
      atomicMax(slot + bf, pk);
    }
  }
}

// K3: write Rp and Rn; k_fin folded in (winners re-derived from packed, 2 u64
// L2 loads per block). Block-uniform branch on {f==lo, f==hi, else} so the
// common case issues exactly 1 load + 2 NT stores per float4.
__global__ void k_write(const float* __restrict__ x, const float* __restrict__ inv_norm,
                        const float* __restrict__ mem1, const float* __restrict__ mem2,
                        const int* __restrict__ high_idx, const int* __restrict__ low_idx,
                        const unsigned long long* __restrict__ packed,
                        float* __restrict__ outp){
  int bid = blockIdx.x;          // 0..2559
  int tid = threadIdx.x;
  int fid = bid >> 3;            // (q*4+b)*20+f, 0..319
  int part = bid & 7;
  int q = fid / 80;
  int rem = fid - q*80;
  int b = rem / F_;
  int f = rem - b*F_;
  int t16 = b*4 + q;
  int lo = __ldg(low_idx + t16), hi = __ldg(high_idx + t16);

  // index outputs (former k_fin), once
  if (bid == 0 && tid < 16){
    int tb = tid >> 2, tq = tid & 3;
    int thi = __ldg(high_idx + tid), tlo = __ldg(low_idx + tid);
    int s2hi = (int)(unsigned int)__ldg(packed + 80 + tb*F_ + thi);
    int s1lo = (int)(unsigned int)__ldg(packed +      tb*F_ + tlo);
    outp[OUT_TAIL      + tq*4 + tb] = (float)s2hi; // high_sim, order (q,b)
    outp[OUT_TAIL + 16 + tq*4 + tb] = (float)s1lo; // low_sim
  }

  __shared__ float sinv[OBJ];
  if (tid < OBJ) sinv[tid] = inv_norm[(b*F_ + f)*OBJ + tid];
  __syncthreads();

  const float4* xf = (const float4*)x + (size_t)(b*F_ + f)*FRAME_F4;
  float4* o4 = (float4*)outp;
  size_t fbase = (size_t)fid * FRAME_F4;

  if (f == lo){
    int rpRow = (int)(unsigned int)__ldg(packed + b*F_ + lo);
    const float4* m1p = (const float4*)mem1 + (size_t)rpRow * FRAME_F4;
    #pragma unroll
    for (int k = 0; k < 10; k++){
      int e4 = part*2560 + k*256 + tid;
      float s = sinv[(part*10 + k) >> 2];     // o is uniform per k-iteration
      float4 xn = f4scale(__ldg(xf + e4), s);
      ntst(o4 + fbase + e4, __ldg(m1p + e4));
      ntst(o4 + RP_F4 + fbase + e4, xn);
    }
  } else if (f == hi){
    int rnRow = (int)(unsigned int)__ldg(packed + 80 + b*F_ + lo); // gathered at LOW idx
    const float4* m2p = (const float4*)mem2 + (size_t)rnRow * FRAME_F4;
    #pragma unroll
    for (int k = 0; k < 10; k++){
      int e4 = part*2560 + k*256 + tid;
      float s = sinv[(part*10 + k) >> 2];
      float4 xn = f4scale(__ldg(xf + e4), s);
      ntst(o4 + fbase + e4, xn);
      ntst(o4 + RP_F4 + fbase + e4, __ldg(m2p + e4));
    }
  } else {
    #pragma unroll
    for (int k = 0; k < 10; k++){
      int e4 = part*2560 + k*256 + tid;
      float s = sinv[(part*10 + k) >> 2];
      float4 xn = f4scale(__ldg(xf + e4), s);
      ntst(o4 + fbase + e4, xn);
      ntst(o4 + RP_F4 + fbase + e4, xn);
    }
  }
}

extern "C" void kernel_launch(void* const* d_in, const int* in_sizes, int n_in,
                              void* d_out, int out_size, void* d_ws, size_t ws_size,
                              hipStream_t stream) {
  const float* qr       = (const float*)d_in[0]; // [4,4,20]
  const float* x        = (const float*)d_in[1]; // [4,20,20,4096]
  const float* mem1     = (const float*)d_in[2]; // [1000, 81920]
  const float* mem2     = (const float*)d_in[3];
  const int*   rand_idx = (const int*)  d_in[4]; // [4,4,1]
  float* outp = (float*)d_out;

  // ws layout (floats): mpn1 | mpn2 | rmaxn | inv_norm | packed | idx arrays
  float* mpn1     = (float*)d_ws;                       // 4,096,000
  float* mpn2     = mpn1 + 4096000;                     // 4,096,000
  float* rmaxn    = mpn2 + 4096000;                     // 327,680
  float* inv_norm = rmaxn + 327680;                     // 1,600
  unsigned long long* packed = (unsigned long long*)(inv_norm + 1600); // 160 u64 (8B-aligned)
  int*   high_idx = (int*)(packed + 160);               // 16
  int*   low_idx  = high_idx + 16;                      // 16

  k_fused1<<<2081, 256, 0, stream>>>(x, mem1, mem2, qr, rand_idx,
                                     mpn1, mpn2, rmaxn, inv_norm,
                                     packed, high_idx, low_idx);
  k_dots  <<<500,  256, 0, stream>>>(mpn1, mpn2, rmaxn, packed);
  k_write <<<2560, 256, 0, stream>>>(x, inv_norm, mem1, mem2,
                                     high_idx, low_idx, packed, outp);
}

// Round 2
// 792.085 us; speedup vs baseline: 1.3694x; 1.3694x over previous
//
#include <hip/hip_runtime.h>

// Problem constants
#define D 4096
#define OBJ 20
#define M_MEM 1000
#define F_ 20
// frames out = Q*B*F = 320; frame elems = OBJ*D = 81920 (=20480 float4)
// out layout: Rp [320*81920] | Rn [320*81920] | high_sim [16] | low_sim [16]
#define FRAME_F4 20480
#define RP_F4 6553600
#define OUT_TAIL 52428800

typedef float vf4 __attribute__((ext_vector_type(4)));

__device__ __forceinline__ float4 f4max(float4 a, float4 b){
  return make_float4(fmaxf(a.x,b.x), fmaxf(a.y,b.y), fmaxf(a.z,b.z), fmaxf(a.w,b.w));
}
__device__ __forceinline__ float4 f4scale(float4 a, float s){
  return make_float4(a.x*s, a.y*s, a.z*s, a.w*s);
}
__device__ __forceinline__ double f4ss(float4 a){
  return (double)a.x*a.x + (double)a.y*a.y + (double)a.z*a.z + (double)a.w*a.w;
}
// nontemporal float4 store (output is never re-read on device)
__device__ __forceinline__ void ntst(float4* p, float4 v){
  vf4 t; t.x = v.x; t.y = v.y; t.z = v.z; t.w = v.w;
  __builtin_nontemporal_store(t, (vf4*)p);
}
// nontemporal float4 load (streams with zero reuse: evict-first, don't thrash L2)
__device__ __forceinline__ float4 ntld(const float4* p){
  vf4 t = __builtin_nontemporal_load((const vf4*)p);
  return make_float4(t.x, t.y, t.z, t.w);
}

// monotone u32 key for float (handles negatives)
__device__ __forceinline__ unsigned int fkey(float f){
  unsigned int b = __float_as_uint(f);
  return (b & 0x80000000u) ? ~b : (b | 0x80000000u);
}

// 256-thread block sum reduce (f64), result broadcast to all threads
__device__ __forceinline__ double blockReduce256(double v){
  #pragma unroll
  for (int off = 32; off > 0; off >>= 1) v += __shfl_down(v, off, 64);
  __shared__ double sh[4];
  int w = threadIdx.x >> 6;
  if ((threadIdx.x & 63) == 0) sh[w] = v;
  __syncthreads();
  return sh[0] + sh[1] + sh[2] + sh[3];
}

// K1: one grid, three roles.
//  blocks 80..2079 : mem max-pool + L2-normalize (the 655 MB stream, NT loads)
//  blocks  0..79   : fused per-frame row norms (wave-per-row) + max-pool + normalize
//  block  2080     : high/low frame selection + zero packed[]
__global__ void k_fused1(const float* __restrict__ x,
                         const float* __restrict__ mem1, const float* __restrict__ mem2,
                         const float* __restrict__ qr, const int* __restrict__ rand_idx,
                         float* __restrict__ mpn1, float* __restrict__ mpn2,
                         float* __restrict__ rmaxn, float* __restrict__ inv_norm,
                         unsigned long long* __restrict__ packed,
                         int* __restrict__ high_idx, int* __restrict__ low_idx){
  int blk = blockIdx.x;
  int tid = threadIdx.x;
  if (blk >= 80 && blk < 2080){
    int id = blk - 80;
    const float* mem; float* outp; int m;
    if (id < M_MEM){ mem = mem1; outp = mpn1; m = id; }
    else           { mem = mem2; outp = mpn2; m = id - M_MEM; }
    const float4* base = (const float4*)mem + (size_t)m * FRAME_F4;
    float4 mv[4];
    #pragma unroll
    for (int i = 0; i < 4; i++) mv[i] = make_float4(-INFINITY,-INFINITY,-INFINITY,-INFINITY);
    for (int o = 0; o < OBJ; o++){
      const float4* p = base + o*1024;
      #pragma unroll
      for (int i = 0; i < 4; i++) mv[i] = f4max(mv[i], ntld(p + tid + i*256));
    }
    double ss = 0.0;
    #pragma unroll
    for (int i = 0; i < 4; i++) ss += f4ss(mv[i]);
    ss = blockReduce256(ss);
    float rinv = (float)(1.0 / fmax(sqrt(ss), 1e-12));
    float4* o4 = (float4*)outp + (size_t)m * 1024;
    #pragma unroll
    for (int i = 0; i < 4; i++) o4[tid + i*256] = f4scale(mv[i], rinv);
  } else if (blk < 80){
    // frame blk = b*20+f. Pass 1: wave w computes norms of rows 5w..5w+4 (no block sync).
    __shared__ float sinv[OBJ];
    int w = tid >> 6, lane = tid & 63;
    const float4* base = (const float4*)x + (size_t)blk * FRAME_F4;
    for (int o = w*5; o < w*5 + 5; o++){
      const float4* p = base + o*1024;
      double ss = 0.0;
      #pragma unroll
      for (int j = 0; j < 16; j++) ss += f4ss(__ldg(p + j*64 + lane));
      #pragma unroll
      for (int off = 32; off > 0; off >>= 1) ss += __shfl_down(ss, off, 64);
      if (lane == 0){
        float inv = (float)(1.0 / fmax(sqrt(ss), 1e-12));
        sinv[o] = inv;
        inv_norm[blk*OBJ + o] = inv;
      }
    }
    __syncthreads();
    // Pass 2: scaled max-pool over rows (re-reads frame from L2) + normalize.
    float4 mv[4];
    #pragma unroll
    for (int i = 0; i < 4; i++) mv[i] = make_float4(-INFINITY,-INFINITY,-INFINITY,-INFINITY);
    for (int o = 0; o < OBJ; o++){
      float s = sinv[o];
      const float4* p = base + o*1024;
      #pragma unroll
      for (int i = 0; i < 4; i++) mv[i] = f4max(mv[i], f4scale(__ldg(p + tid + i*256), s));
    }
    double ss = 0.0;
    #pragma unroll
    for (int i = 0; i < 4; i++) ss += f4ss(mv[i]);
    ss = blockReduce256(ss);
    float rinv = (float)(1.0 / fmax(sqrt(ss), 1e-12));
    float4* outp = (float4*)rmaxn + (size_t)blk * 1024;
    #pragma unroll
    for (int i = 0; i < 4; i++) outp[tid + i*256] = f4scale(mv[i], rinv);
  } else {
    int t = tid;
    if (t < 160) packed[t] = 0ull;
    if (t < 16){
      float wv[F_];
      for (int f = 0; f < F_; f++) wv[f] = qr[t*F_ + f];
      int hi = 0; float hv = wv[0];
      for (int f = 1; f < F_; f++) if (wv[f] > hv){ hv = wv[f]; hi = f; }
      int r = rand_idx[t];
      bool used[F_];
      for (int f = 0; f < F_; f++) used[f] = false;
      used[hi] = true;
      int li = 0;
      for (int it = 0; it <= r; it++){
        int bi = -1; float bv = INFINITY;
        for (int f = 0; f < F_; f++) if (!used[f] && wv[f] < bv){ bv = wv[f]; bi = f; }
        used[bi] = true; li = bi;
      }
      high_idx[t] = hi; low_idx[t] = li;
    }
  }
}

// K2: dots of 80 rmaxn rows vs 4 LDS-staged mem_mpn rows.
// NT staging loads keep the one-shot mpn stream from evicting rmaxn out of L2
// (r1 showed 1.05 GB of L2-miss traffic = the 500x rmaxn re-read falling through).
// Each wave owns 20 contiguous bf rows; acc[20][4] lives in registers; per
// D-chunk we read the 4 LDS m-rows once and stream 20 rrow loads against them.
__global__ void __launch_bounds__(256, 2)
k_dots(const float* __restrict__ mpn1, const float* __restrict__ mpn2,
       const float* __restrict__ rmaxn,
       unsigned long long* __restrict__ packed){
  int blk = blockIdx.x;         // 0..499
  int which = blk / 250;        // 0 -> mem1, 1 -> mem2
  int chunk = blk % 250;        // 4 m-rows per chunk
  const float* mpn = which ? mpn2 : mpn1;
  __shared__ float4 rows[4*1024];   // 64 KB
  const float4* src = (const float4*)mpn + (size_t)chunk * 4096;
  for (int i = threadIdx.x; i < 4096; i += 256) rows[i] = ntld(src + i);
  __syncthreads();
  int w = threadIdx.x >> 6, lane = threadIdx.x & 63;
  const float4* rbase = (const float4*)rmaxn + (size_t)(w*20) * 1024 + lane;
  float acc[20][4];
  #pragma unroll
  for (int j = 0; j < 20; j++){
    acc[j][0] = 0.f; acc[j][1] = 0.f; acc[j][2] = 0.f; acc[j][3] = 0.f;
  }
  for (int i = 0; i < 16; i++){
    float4 m0 = rows[       i*64 + lane];
    float4 m1 = rows[1024 + i*64 + lane];
    float4 m2 = rows[2048 + i*64 + lane];
    float4 m3 = rows[3072 + i*64 + lane];
    #pragma unroll
    for (int j = 0; j < 20; j++){
      float4 r = __ldg(rbase + (size_t)j*1024 + i*64);
      acc[j][0] += r.x*m0.x + r.y*m0.y + r.z*m0.z + r.w*m0.w;
      acc[j][1] += r.x*m1.x + r.y*m1.y + r.z*m1.z + r.w*m1.w;
      acc[j][2] += r.x*m2.x + r.y*m2.y + r.z*m2.z + r.w*m2.w;
      acc[j][3] += r.x*m3.x + r.y*m3.y + r.z*m3.z + r.w*m3.w;
    }
  }
  unsigned long long* slot = packed + which*80 + w*20;
  #pragma unroll
  for (int j = 0; j < 20; j++){
    float s0 = acc[j][0], s1 = acc[j][1], s2 = acc[j][2], s3 = acc[j][3];
    #pragma unroll
    for (int off = 32; off > 0; off >>= 1){
      s0 += __shfl_down(s0, off, 64);
      s1 += __shfl_down(s1, off, 64);
      s2 += __shfl_down(s2, off, 64);
      s3 += __shfl_down(s3, off, 64);
    }
    if (lane == 0){
      float best = s0; int bi = 0;
      if (s1 > best){ best = s1; bi = 1; }
      if (s2 > best){ best = s2; bi = 2; }
      if (s3 > best){ best = s3; bi = 3; }
      unsigned long long pk = ((unsigned long long)fkey(best) << 32) |
                              (unsigned int)(chunk*4 + bi);
      atomicMax(slot + j, pk);
    }
  }
}

// K3: write Rp and Rn; k_fin folded in (winners re-derived from packed, 2 u64
// L2 loads per block). Block-uniform branch on {f==lo, f==hi, else} so the
// common case issues exactly 1 load + 2 NT stores per float4.
__global__ void k_write(const float* __restrict__ x, const float* __restrict__ inv_norm,
                        const float* __restrict__ mem1, const float* __restrict__ mem2,
                        const int* __restrict__ high_idx, const int* __restrict__ low_idx,
                        const unsigned long long* __restrict__ packed,
                        float* __restrict__ outp){
  int bid = blockIdx.x;          // 0..2559
  int tid = threadIdx.x;
  int fid = bid >> 3;            // (q*4+b)*20+f, 0..319
  int part = bid & 7;
  int q = fid / 80;
  int rem = fid - q*80;
  int b = rem / F_;
  int f = rem - b*F_;
  int t16 = b*4 + q;
  int lo = __ldg(low_idx + t16), hi = __ldg(high_idx + t16);

  // index outputs (former k_fin), once
  if (bid == 0 && tid < 16){
    int tb = tid >> 2, tq = tid & 3;
    int thi = __ldg(high_idx + tid), tlo = __ldg(low_idx + tid);
    int s2hi = (int)(unsigned int)__ldg(packed + 80 + tb*F_ + thi);
    int s1lo = (int)(unsigned int)__ldg(packed +      tb*F_ + tlo);
    outp[OUT_TAIL      + tq*4 + tb] = (float)s2hi; // high_sim, order (q,b)
    outp[OUT_TAIL + 16 + tq*4 + tb] = (float)s1lo; // low_sim
  }

  __shared__ float sinv[OBJ];
  if (tid < OBJ) sinv[tid] = inv_norm[(b*F_ + f)*OBJ + tid];
  __syncthreads();

  const float4* xf = (const float4*)x + (size_t)(b*F_ + f)*FRAME_F4;
  float4* o4 = (float4*)outp;
  size_t fbase = (size_t)fid * FRAME_F4;

  if (f == lo){
    int rpRow = (int)(unsigned int)__ldg(packed + b*F_ + lo);
    const float4* m1p = (const float4*)mem1 + (size_t)rpRow * FRAME_F4;
    #pragma unroll
    for (int k = 0; k < 10; k++){
      int e4 = part*2560 + k*256 + tid;
      float s = sinv[(part*10 + k) >> 2];     // o is uniform per k-iteration
      float4 xn = f4scale(__ldg(xf + e4), s);
      ntst(o4 + fbase + e4, __ldg(m1p + e4));
      ntst(o4 + RP_F4 + fbase + e4, xn);
    }
  } else if (f == hi){
    int rnRow = (int)(unsigned int)__ldg(packed + 80 + b*F_ + lo); // gathered at LOW idx
    const float4* m2p = (const float4*)mem2 + (size_t)rnRow * FRAME_F4;
    #pragma unroll
    for (int k = 0; k < 10; k++){
      int e4 = part*2560 + k*256 + tid;
      float s = sinv[(part*10 + k) >> 2];
      float4 xn = f4scale(__ldg(xf + e4), s);
      ntst(o4 + fbase + e4, xn);
      ntst(o4 + RP_F4 + fbase + e4, __ldg(m2p + e4));
    }
  } else {
    #pragma unroll
    for (int k = 0; k < 10; k++){
      int e4 = part*2560 + k*256 + tid;
      float s = sinv[(part*10 + k) >> 2];
      float4 xn = f4scale(__ldg(xf + e4), s);
      ntst(o4 + fbase + e4, xn);
      ntst(o4 + RP_F4 + fbase + e4, xn);
    }
  }
}

extern "C" void kernel_launch(void* const* d_in, const int* in_sizes, int n_in,
                              void* d_out, int out_size, void* d_ws, size_t ws_size,
                              hipStream_t stream) {
  const float* qr       = (const float*)d_in[0]; // [4,4,20]
  const float* x        = (const float*)d_in[1]; // [4,20,20,4096]
  const float* mem1     = (const float*)d_in[2]; // [1000, 81920]
  const float* mem2     = (const float*)d_in[3];
  const int*   rand_idx = (const int*)  d_in[4]; // [4,4,1]
  float* outp = (float*)d_out;

  // ws layout (floats): mpn1 | mpn2 | rmaxn | inv_norm | packed | idx arrays
  float* mpn1     = (float*)d_ws;                       // 4,096,000
  float* mpn2     = mpn1 + 4096000;                     // 4,096,000
  float* rmaxn    = mpn2 + 4096000;                     // 327,680
  float* inv_norm = rmaxn + 327680;                     // 1,600
  unsigned long long* packed = (unsigned long long*)(inv_norm + 1600); // 160 u64 (8B-aligned)
  int*   high_idx = (int*)(packed + 160);               // 16
  int*   low_idx  = high_idx + 16;                      // 16

  k_fused1<<<2081, 256, 0, stream>>>(x, mem1, mem2, qr, rand_idx,
                                     mpn1, mpn2, rmaxn, inv_norm,
                                     packed, high_idx, low_idx);
  k_dots  <<<500,  256, 0, stream>>>(mpn1, mpn2, rmaxn, packed);
  k_write <<<2560, 256, 0, stream>>>(x, inv_norm, mem1, mem2,
                                     high_idx, low_idx, packed, outp);
}